// Round 3
// baseline (133.412 us; speedup 1.0000x reference)
//
#include <hip/hip_runtime.h>

// Depthwise Gaussian blur K=121, replicate pad, separable, fp32. FUSED.
// R10: H phase re-geometried to ONE contiguous 16-col span per lane
// (cols 16L..16L+15). Window = 136 cols = 17 groups vs R9's two disjoint
// 8-col spans (2x19 groups) -> HALF the ds_read_b128 and half the
// conflict cycles in the LDS-pipe-bound H phase (R9 A/B: occupancy
// +33% with flat dur => per-CU LDS pipe is the limit, not waves).
// Also: interior row-tiles (47/64) take a clamp-free V path with a
// running row pointer (saves ~4 VALU x 136 loads).
// Kept from R9: 16B-unit XOR swizzle (u^=(u>>3)&7) zero-pad LDS,
// deferred normalization (1/S^2 at the end), f4 halo fill.

#define HH    512
#define WW    512
#define PLANE (512 * 512)
#define NIMG  24
#define ROWF  640                    // 160 16B-units/row, swizzle-bijective

__device__ __forceinline__ void make_weights(const float* __restrict__ sigma,
                                             float* __restrict__ wlds, int tid) {
    if (tid < 128) {
        const float s = sigma[0] * 8.0f + 16.0f;
        const float inv2v = 1.0f / (2.0f * s * s);
        float g = 0.0f;
        if (tid < 121) {
            const float c = (float)tid - 60.0f;
            g = __expf(-c * c * inv2v);
        }
        wlds[tid] = g;               // UNNORMALIZED; taps 121..127 exactly 0
    }
}

// dword offset within an LDS row for padded column `col` (swizzled)
__device__ __forceinline__ int swz_off(int col) {
    const int u = col >> 2;
    return ((u ^ ((u >> 3) & 7)) << 2) + (col & 3);
}

// Vertical octet, clamped rows (boundary tiles)
#define V_OCT(CUR, NXT, KO)                                               \
    { *(float4*)&wq[0] = *(const float4*)&wlds[(KO) * 8];                 \
      *(float4*)&wq[4] = *(const float4*)&wlds[(KO) * 8 + 4];             \
      _Pragma("unroll")                                                   \
      for (int ki = 0; ki < 8; ++ki) {                                    \
          int rr = r0 - 52 + (KO) * 8 + ki;                               \
          rr = rr < 0 ? 0 : (rr > HH - 1 ? HH - 1 : rr);                  \
          NXT[ki] = *(const float2*)&src[(size_t)rr * WW];                \
          const float wk = wq[ki];                                        \
          _Pragma("unroll")                                               \
          for (int j = 0; j < 8; ++j) {                                   \
              const int idx = ki + j;                                     \
              const float2 v = (idx < 8) ? CUR[idx] : NXT[idx - 8];       \
              vac[j].x += wk * v.x; vac[j].y += wk * v.y;                 \
          }                                                               \
      }                                                                   \
    }

// Vertical octet, no clamp (interior tiles): running row pointer pv
#define V_OCT_NC(CUR, NXT, KO)                                            \
    { *(float4*)&wq[0] = *(const float4*)&wlds[(KO) * 8];                 \
      *(float4*)&wq[4] = *(const float4*)&wlds[(KO) * 8 + 4];             \
      _Pragma("unroll")                                                   \
      for (int ki = 0; ki < 8; ++ki) {                                    \
          NXT[ki] = *(const float2*)pv; pv += WW;                         \
          const float wk = wq[ki];                                        \
          _Pragma("unroll")                                               \
          for (int j = 0; j < 8; ++j) {                                   \
              const int idx = ki + j;                                     \
              const float2 v = (idx < 8) ? CUR[idx] : NXT[idx - 8];       \
              vac[j].x += wk * v.x; vac[j].y += wk * v.y;                 \
          }                                                               \
      }                                                                   \
    }

// Load group G (8 floats): phys(2G+1) = phys(2G)^1 -> one addr calc / 2 b128
#define LOADG(D, G)                                                       \
    { const int u_  = 2 * (G);                                            \
      const int o1_ = (u_ ^ ((u_ >> 3) & 7)) << 2;                        \
      *(float4*)&D[0] = *(const float4*)(bs + o1_);                       \
      *(float4*)&D[4] = *(const float4*)(bs + (o1_ ^ 4)); }

// One octet over a contiguous 16-col span; window groups A0..A2, prefetch A3
#define H_OCT(A0, A1, A2, A3, KO)                                         \
    { LOADG(A3, 2 * L + (KO) + 3)                                         \
      *(float4*)&wq[0] = *(const float4*)&wlds[(KO) * 8];                 \
      *(float4*)&wq[4] = *(const float4*)&wlds[(KO) * 8 + 4];             \
      _Pragma("unroll")                                                   \
      for (int ki = 0; ki < 8; ++ki) {                                    \
          const float wk = wq[ki];                                        \
          _Pragma("unroll")                                               \
          for (int j = 0; j < 16; ++j) {                                  \
              const int idx = ki + j;                                     \
              const float v = (idx < 8) ? A0[idx]                         \
                            : (idx < 16) ? A1[idx - 8] : A2[idx - 16];    \
              acc[j] += wk * v;                                           \
          }                                                               \
      }                                                                   \
    }

// Final octet: no prefetch (group 2L+18 would run past the row)
#define H_OCT_NP(A0, A1, A2, A3, KO)                                      \
    { *(float4*)&wq[0] = *(const float4*)&wlds[(KO) * 8];                 \
      *(float4*)&wq[4] = *(const float4*)&wlds[(KO) * 8 + 4];             \
      _Pragma("unroll")                                                   \
      for (int ki = 0; ki < 8; ++ki) {                                    \
          const float wk = wq[ki];                                        \
          _Pragma("unroll")                                               \
          for (int j = 0; j < 16; ++j) {                                  \
              const int idx = ki + j;                                     \
              const float v = (idx < 8) ? A0[idx]                         \
                            : (idx < 16) ? A1[idx - 8] : A2[idx - 16];    \
              acc[j] += wk * v;                                           \
          }                                                               \
      }                                                                   \
    }

__global__ __launch_bounds__(256, 6) void blur_fused(
        const float* __restrict__ x, const float* __restrict__ sigma,
        float* __restrict__ out) {
    __shared__ float sm[8 * ROWF];                   // 20480 B
    __shared__ float wlds[128];
    const int tid = threadIdx.x;

    // XCD swizzle: linear id -> contiguous 192-tile span per XCD (%8 rr).
    const int lid   = blockIdx.x + gridDim.x * blockIdx.y;   // 0..1535
    const int tile  = (lid & 7) * 192 + (lid >> 3);
    const int r0    = (tile & 63) * 8;               // output rows r0..r0+7
    const int plane = tile >> 6;

    const int c0 = tid * 2;                          // this thread's 2 cols
    const float* __restrict__ src = x + (size_t)plane * PLANE + c0;

    // ---- vertical: 8 rows x 2 cols per thread, global-streamed window ----
    float2 wa[8], wb[8], vac[8];
    float  wq[8];
    const bool interior = (r0 >= 64) && (r0 <= 432);   // rows r0-60..r0+75 in-range
    if (interior) {
        const float* pp = src + (size_t)(r0 - 60) * WW;
        #pragma unroll
        for (int m = 0; m < 8; ++m) { wa[m] = *(const float2*)pp; pp += WW; }
    } else {
        #pragma unroll
        for (int m = 0; m < 8; ++m) {                // rows r0-60..r0-53
            int rr = r0 - 60 + m;
            rr = rr < 0 ? 0 : rr;
            wa[m] = *(const float2*)&src[(size_t)rr * WW];
        }
    }
    make_weights(sigma, wlds, tid);                  // overlaps loads in flight
    #pragma unroll
    for (int j = 0; j < 8; ++j) vac[j] = make_float2(0.f, 0.f);
    __syncthreads();                                 // wlds ready

    // normalizer: S = sum of taps, once per wave (butterfly), scale at end
    const int lane = tid & 63;
    float s_sum = wlds[lane] + wlds[lane + 64];
    #pragma unroll
    for (int o = 32; o >= 1; o >>= 1) s_sum += __shfl_xor(s_sum, o);
    const float inv_s2 = 1.0f / (s_sum * s_sum);

    if (interior) {
        const float* pv = src + (size_t)(r0 - 52) * WW;
        #pragma unroll 1
        for (int ko = 0; ko < 16; ko += 2) {
            V_OCT_NC(wa, wb, ko)
            V_OCT_NC(wb, wa, ko + 1)
        }
    } else {
        #pragma unroll 1
        for (int ko = 0; ko < 16; ko += 2) {
            V_OCT(wa, wb, ko)
            V_OCT(wb, wa, ko + 1)
        }
    }

    // write intermediate at halo offset +60 (swizzled; float2 stays in-unit)
    {
        const int off = swz_off(c0 + 60);            // col even -> within-unit
        #pragma unroll
        for (int j = 0; j < 8; ++j)
            *(float2*)&sm[j * ROWF + off] = vac[j];
    }
    __syncthreads();

    // ---- halo: cols 0..59 <- col 60; 572..639 <- col 571 -----------------
    // (cols 632..639 are only touched by zero taps; replicate value is fine)
    if (tid < 32) {
        const int p = (tid < 15) ? tid * 4 : 572 + (tid - 15) * 4;
        const int u   = p >> 2;
        const int off = (u ^ ((u >> 3) & 7)) << 2;   // 16B-aligned
        const int soff = (tid < 15) ? swz_off(60) : swz_off(571);
        #pragma unroll
        for (int r8 = 0; r8 < 8; ++r8) {
            const float v = sm[r8 * ROWF + soff];
            *(float4*)&sm[r8 * ROWF + off] = make_float4(v, v, v, v);
        }
    }
    __syncthreads();

    // ---- horizontal: ONE contiguous 16-col span per lane -----------------
    const int r = tid >> 5;                          // 0..7
    const int L = tid & 31;                          // span cols 16L..16L+15
    const float* __restrict__ bs = sm + r * ROWF;

    float a0[8], a1[8], a2[8], a3[8];
    float acc[16];
    #pragma unroll
    for (int j = 0; j < 16; ++j) acc[j] = 0.0f;

    LOADG(a0, 2 * L)
    LOADG(a1, 2 * L + 1)
    LOADG(a2, 2 * L + 2)

    #pragma unroll 1
    for (int ko = 0; ko < 12; ko += 4) {
        H_OCT(a0, a1, a2, a3, ko)
        H_OCT(a1, a2, a3, a0, ko + 1)
        H_OCT(a2, a3, a0, a1, ko + 2)
        H_OCT(a3, a0, a1, a2, ko + 3)
    }
    H_OCT   (a0, a1, a2, a3, 12)
    H_OCT   (a1, a2, a3, a0, 13)
    H_OCT   (a2, a3, a0, a1, 14)
    H_OCT_NP(a3, a0, a1, a2, 15)

    float* __restrict__ dst = out + (size_t)plane * PLANE
                                  + (size_t)(r0 + r) * WW + L * 16;
    const float k2 = inv_s2;
    *(float4*)(dst)      = make_float4(acc[0]  * k2, acc[1]  * k2,
                                       acc[2]  * k2, acc[3]  * k2);
    *(float4*)(dst + 4)  = make_float4(acc[4]  * k2, acc[5]  * k2,
                                       acc[6]  * k2, acc[7]  * k2);
    *(float4*)(dst + 8)  = make_float4(acc[8]  * k2, acc[9]  * k2,
                                       acc[10] * k2, acc[11] * k2);
    *(float4*)(dst + 12) = make_float4(acc[12] * k2, acc[13] * k2,
                                       acc[14] * k2, acc[15] * k2);
}

extern "C" void kernel_launch(void* const* d_in, const int* in_sizes, int n_in,
                              void* d_out, int out_size, void* d_ws, size_t ws_size,
                              hipStream_t stream) {
    const float* x     = (const float*)d_in[0];
    const float* sigma = (const float*)d_in[1];
    float* out = (float*)d_out;
    blur_fused<<<dim3(HH / 8, NIMG), dim3(256), 0, stream>>>(x, sigma, out);
}